// Round 1
// baseline (2968.041 us; speedup 1.0000x reference)
//
#include <hip/hip_runtime.h>
#include <hip/hip_bf16.h>
#include <math.h>

#define N_NODES 100000
#define N_RELS 16
#define N_EDGES 1600000
#define DD 64
#define OUTW 136   // 64+32+16+16+8
#define NEG_SLOPE 0.01f

__device__ __forceinline__ float lrelu(float x) { return x >= 0.f ? x : NEG_SLOPE * x; }

// ---------------- K0: CSR offsets over sorted dst ----------------
__global__ void k_offsets(const int* __restrict__ dst, int* __restrict__ offs) {
    int n = blockIdx.x * blockDim.x + threadIdx.x;
    if (n > N_NODES) return;
    int lo = 0, hi = N_EDGES;
    while (lo < hi) {
        int mid = (lo + hi) >> 1;
        if (dst[mid] < n) lo = mid + 1; else hi = mid;
    }
    offs[n] = lo;
}

// ---------------- K1: per-relation GEMM  buf = emb @ W_R[r]  (N x 64)(64 x 64) ----------------
#define GM 128
__global__ __launch_bounds__(256) void k_gemm_rel(const float* __restrict__ A,
                                                  const float* __restrict__ W,
                                                  float* __restrict__ C) {
    __shared__ float AsT[64][GM + 4];   // [k][row], row-stride 132 floats (528B, 16B-aligned)
    __shared__ float Ws[64][68];        // [k][col], row-stride 272B
    const int tid = threadIdx.x;
    const size_t row0 = (size_t)blockIdx.x * GM;

    // load A tile (GM x 64), store transposed
    for (int i = 0; i < 8; ++i) {
        int v = i * 256 + tid;            // float4 index, 0..2047
        int r = v >> 4, kc = (v & 15) * 4;
        size_t gr = row0 + r;
        float4 a = (gr < N_NODES) ? *(const float4*)(A + gr * 64 + kc)
                                  : make_float4(0.f, 0.f, 0.f, 0.f);
        AsT[kc + 0][r] = a.x; AsT[kc + 1][r] = a.y;
        AsT[kc + 2][r] = a.z; AsT[kc + 3][r] = a.w;
    }
    // load W (64 x 64)
    for (int i = 0; i < 4; ++i) {
        int v = i * 256 + tid;            // float4 index, 0..1023
        int r = v >> 4, c = (v & 15) * 4;
        float4 w = *(const float4*)(W + (size_t)v * 4);
        Ws[r][c + 0] = w.x; Ws[r][c + 1] = w.y; Ws[r][c + 2] = w.z; Ws[r][c + 3] = w.w;
    }
    __syncthreads();

    const int rg = tid >> 4, cg = tid & 15;   // 16 row-groups x 16 col-groups
    const int r0 = rg * 8, c0 = cg * 4;       // thread tile 8x4
    float acc[8][4] = {};
    #pragma unroll 4
    for (int k = 0; k < 64; ++k) {
        float4 a0 = *(float4*)&AsT[k][r0];
        float4 a1 = *(float4*)&AsT[k][r0 + 4];
        float4 b  = *(float4*)&Ws[k][c0];
        float av[8] = {a0.x, a0.y, a0.z, a0.w, a1.x, a1.y, a1.z, a1.w};
        float bv[4] = {b.x, b.y, b.z, b.w};
        #pragma unroll
        for (int i = 0; i < 8; ++i)
            #pragma unroll
            for (int j = 0; j < 4; ++j) acc[i][j] += av[i] * bv[j];
    }
    for (int i = 0; i < 8; ++i) {
        size_t gr = row0 + r0 + i;
        if (gr < N_NODES)
            *(float4*)(C + gr * 64 + c0) = make_float4(acc[i][0], acc[i][1], acc[i][2], acc[i][3]);
    }
}

// ---------------- K2: raw attention scores for edges of relation r ----------------
__global__ __launch_bounds__(256) void k_edge_att(const float* __restrict__ buf,
                                                  const float* __restrict__ rel,
                                                  const int* __restrict__ src,
                                                  const int* __restrict__ etype,
                                                  const int* __restrict__ dstv,
                                                  int r, float* __restrict__ att) {
    int wave = threadIdx.x >> 6, lane = threadIdx.x & 63;
    long e = (long)blockIdx.x * 4 + wave;
    if (e >= N_EDGES) return;
    if (etype[e] != r) return;
    int s = src[e], dn = dstv[e];
    float t = buf[(size_t)s * 64 + lane];
    float h = buf[(size_t)dn * 64 + lane];
    float v = t * tanhf(h + rel[lane]);
    for (int off = 32; off > 0; off >>= 1) v += __shfl_down(v, off);
    if (lane == 0) att[e] = v;
}

// ---------------- K3: per-dst-node softmax over att (in place) ----------------
__global__ void k_softmax(float* __restrict__ att, const int* __restrict__ offs) {
    int n = blockIdx.x * blockDim.x + threadIdx.x;
    if (n >= N_NODES) return;
    int b = offs[n], ee = offs[n + 1];
    if (b >= ee) return;
    float m = -INFINITY;
    for (int e = b; e < ee; ++e) m = fmaxf(m, att[e]);
    float s = 0.f;
    for (int e = b; e < ee; ++e) s += expf(att[e] - m);
    float inv = 1.f / s;
    for (int e = b; e < ee; ++e) att[e] = expf(att[e] - m) * inv;
}

// ---------------- K4: Nh[n][d] = sum_{e: dst=n} att[e] * ego[src[e]][d] ----------------
__global__ __launch_bounds__(256) void k_aggregate(const float* __restrict__ ego, int din,
                                                   const float* __restrict__ att,
                                                   const int* __restrict__ src,
                                                   const int* __restrict__ offs,
                                                   float* __restrict__ Nh) {
    int wave = threadIdx.x >> 6, lane = threadIdx.x & 63;
    int n = blockIdx.x * 4 + wave;
    if (n >= N_NODES) return;
    int b = offs[n], ee = offs[n + 1];
    if (lane >= din) return;
    float acc = 0.f;
    for (int e = b; e < ee; ++e)
        acc += att[e] * ego[(size_t)src[e] * din + lane];
    Nh[(size_t)n * din + lane] = acc;
}

// ---------------- K5: out[n][j] = lrelu( (x[n] (+Nh[n])) @ W + b ) ----------------
__global__ __launch_bounds__(256) void k_layer(const float* __restrict__ x, size_t soff, int sstride,
                                               const float* __restrict__ Nh,
                                               const float* __restrict__ W, const float* __restrict__ b,
                                               int din, int dout,
                                               float* __restrict__ out, size_t ooff, int ostride) {
    extern __shared__ float Wl[];   // din*dout + dout
    int tid = threadIdx.x;
    int total = din * dout;
    for (int v = tid; v < total; v += 256) Wl[v] = W[v];
    if (tid < dout) Wl[total + tid] = b[tid];
    __syncthreads();
    int npb = 256 / dout;
    int j = tid % dout;
    int n = blockIdx.x * npb + tid / dout;
    if (n >= N_NODES) return;
    float acc = Wl[total + j];
    const float* xr = x + soff + (size_t)n * sstride;
    if (Nh) {
        const float* nr = Nh + (size_t)n * din;
        for (int k = 0; k < din; ++k) acc += (xr[k] + nr[k]) * Wl[k * dout + j];
    } else {
        for (int k = 0; k < din; ++k) acc += xr[k] * Wl[k * dout + j];
    }
    out[ooff + (size_t)n * ostride + j] = lrelu(acc);
}

// ---------------- K6: optional L2-normalize row + broadcast to result blocks ----------------
__global__ __launch_bounds__(256) void k_norm_multi(const float* __restrict__ srcp, size_t soff, int sstride,
                                                    int d, int donorm,
                                                    float* __restrict__ out, int col, int rstart, int rcount) {
    int wave = threadIdx.x >> 6, lane = threadIdx.x & 63;
    int n = blockIdx.x * 4 + wave;
    if (n >= N_NODES) return;
    float v = (lane < d) ? srcp[soff + (size_t)n * sstride + lane] : 0.f;
    float w = v;
    if (donorm) {
        float ss = v * v;
        for (int off = 32; off > 0; off >>= 1) ss += __shfl_down(ss, off);
        ss = __shfl(ss, 0);
        float norm = sqrtf(ss);
        w = v / fmaxf(norm, 1e-12f);
    }
    if (lane < d) {
        for (int rr = 0; rr < rcount; ++rr) {
            size_t base = (size_t)(rstart + rr) * ((size_t)N_NODES * OUTW) + (size_t)n * OUTW + col;
            out[base + lane] = w;
        }
    }
}

extern "C" void kernel_launch(void* const* d_in, const int* in_sizes, int n_in,
                              void* d_out, int out_size, void* d_ws, size_t ws_size,
                              hipStream_t stream) {
    (void)in_sizes; (void)n_in; (void)out_size; (void)ws_size;
    const float* emb = (const float*)d_in[0];
    const float* rel_embed = (const float*)d_in[1];
    const float* W_R = (const float*)d_in[2];
    const float* W0 = (const float*)d_in[3];  const float* b0 = (const float*)d_in[4];
    const float* W1 = (const float*)d_in[5];  const float* b1 = (const float*)d_in[6];
    const float* W2 = (const float*)d_in[7];  const float* b2 = (const float*)d_in[8];
    const float* W3 = (const float*)d_in[9];  const float* b3 = (const float*)d_in[10];
    const int* src = (const int*)d_in[11];
    const int* dst = (const int*)d_in[12];
    const int* etype = (const int*)d_in[13];
    float* out = (float*)d_out;

    char* p = (char*)d_ws;
    auto alloc = [&](size_t bytes) { char* q = p; p += (bytes + 255) & ~(size_t)255; return q; };
    int* offs  = (int*)alloc((size_t)(N_NODES + 1) * 4);
    float* att = (float*)alloc((size_t)N_EDGES * 4);
    float* buf = (float*)alloc((size_t)N_NODES * 64 * 4);   // phase-1 transform; reused as Nh
    float* U1  = (float*)alloc((size_t)N_NODES * 32 * 4);
    float* U2  = (float*)alloc((size_t)N_NODES * 16 * 4);
    float* U3  = (float*)alloc((size_t)N_NODES * 16 * 4);
    float* U4  = (float*)alloc((size_t)N_NODES * 8 * 4);
    float* Nh  = buf;

    const size_t RES = (size_t)N_NODES * OUTW;

    // CSR offsets
    k_offsets<<<(N_NODES + 256) / 256, 256, 0, stream>>>(dst, offs);

    // phase 1: attention scores, relation by relation
    for (int r = 0; r < N_RELS; ++r) {
        k_gemm_rel<<<(N_NODES + GM - 1) / GM, 256, 0, stream>>>(emb, W_R + (size_t)r * 64 * 64, buf);
        k_edge_att<<<N_EDGES / 4, 256, 0, stream>>>(buf, rel_embed + (size_t)r * 64, src, etype, dst, r, att);
    }
    k_softmax<<<(N_NODES + 255) / 256, 256, 0, stream>>>(att, offs);

    // phase 2: aggregation chain A1..A4 (un-normalized in U1..U4)
    k_aggregate<<<(N_NODES + 3) / 4, 256, 0, stream>>>(emb, 64, att, src, offs, Nh);
    k_layer<<<N_NODES / 8, 256, (64 * 32 + 32) * 4, stream>>>(emb, 0, 64, Nh, W0, b0, 64, 32, U1, 0, 32);
    k_aggregate<<<(N_NODES + 3) / 4, 256, 0, stream>>>(U1, 32, att, src, offs, Nh);
    k_layer<<<N_NODES / 16, 256, (32 * 16 + 16) * 4, stream>>>(U1, 0, 32, Nh, W1, b1, 32, 16, U2, 0, 16);
    k_aggregate<<<(N_NODES + 3) / 4, 256, 0, stream>>>(U2, 16, att, src, offs, Nh);
    k_layer<<<N_NODES / 16, 256, (16 * 16 + 16) * 4, stream>>>(U2, 0, 16, Nh, W2, b2, 16, 16, U3, 0, 16);
    k_aggregate<<<(N_NODES + 3) / 4, 256, 0, stream>>>(U3, 16, att, src, offs, Nh);
    k_layer<<<N_NODES / 32, 256, (16 * 8 + 8) * 4, stream>>>(U3, 0, 16, Nh, W3, b3, 16, 8, U4, 0, 8);

    // phase 3: plain-linear chains, written un-normalized into final slots
    // result0: B12 (col96,d16), B13 (col112,d16), B14 (col128,d8)
    k_layer<<<N_NODES / 16, 256, (32 * 16 + 16) * 4, stream>>>(U1, 0, 32, nullptr, W1, b1, 32, 16, out, 0 * RES + 96, OUTW);
    k_layer<<<N_NODES / 16, 256, (16 * 16 + 16) * 4, stream>>>(out, 0 * RES + 96, OUTW, nullptr, W2, b2, 16, 16, out, 0 * RES + 112, OUTW);
    k_layer<<<N_NODES / 32, 256, (16 * 8 + 8) * 4, stream>>>(out, 0 * RES + 112, OUTW, nullptr, W3, b3, 16, 8, out, 0 * RES + 128, OUTW);
    // result1: B23 (col112,d16), B24 (col128,d8)
    k_layer<<<N_NODES / 16, 256, (16 * 16 + 16) * 4, stream>>>(U2, 0, 16, nullptr, W2, b2, 16, 16, out, 1 * RES + 112, OUTW);
    k_layer<<<N_NODES / 32, 256, (16 * 8 + 8) * 4, stream>>>(out, 1 * RES + 112, OUTW, nullptr, W3, b3, 16, 8, out, 1 * RES + 128, OUTW);
    // result2: B34 (col128,d8)
    k_layer<<<N_NODES / 32, 256, (16 * 8 + 8) * 4, stream>>>(U3, 0, 16, nullptr, W3, b3, 16, 8, out, 2 * RES + 128, OUTW);

    // normalize B slots in place (after all dependent reads)
    k_norm_multi<<<(N_NODES + 3) / 4, 256, 0, stream>>>(out, 0 * RES + 96, OUTW, 16, 1, out, 96, 0, 1);
    k_norm_multi<<<(N_NODES + 3) / 4, 256, 0, stream>>>(out, 0 * RES + 112, OUTW, 16, 1, out, 112, 0, 1);
    k_norm_multi<<<(N_NODES + 3) / 4, 256, 0, stream>>>(out, 0 * RES + 128, OUTW, 8, 1, out, 128, 0, 1);
    k_norm_multi<<<(N_NODES + 3) / 4, 256, 0, stream>>>(out, 1 * RES + 112, OUTW, 16, 1, out, 112, 1, 1);
    k_norm_multi<<<(N_NODES + 3) / 4, 256, 0, stream>>>(out, 1 * RES + 128, OUTW, 8, 1, out, 128, 1, 1);
    k_norm_multi<<<(N_NODES + 3) / 4, 256, 0, stream>>>(out, 2 * RES + 128, OUTW, 8, 1, out, 128, 2, 1);

    // broadcast shared blocks: emb copy (no norm) + normalized A1..A4
    k_norm_multi<<<(N_NODES + 3) / 4, 256, 0, stream>>>(emb, 0, 64, 64, 0, out, 0, 0, 4);
    k_norm_multi<<<(N_NODES + 3) / 4, 256, 0, stream>>>(U1, 0, 32, 32, 1, out, 64, 0, 4);
    k_norm_multi<<<(N_NODES + 3) / 4, 256, 0, stream>>>(U2, 0, 16, 16, 1, out, 96, 1, 3);
    k_norm_multi<<<(N_NODES + 3) / 4, 256, 0, stream>>>(U3, 0, 16, 16, 1, out, 112, 2, 2);
    k_norm_multi<<<(N_NODES + 3) / 4, 256, 0, stream>>>(U4, 0, 8, 8, 1, out, 128, 3, 1);
}

// Round 2
// 1149.650 us; speedup vs baseline: 2.5817x; 2.5817x over previous
//
#include <hip/hip_runtime.h>
#include <hip/hip_bf16.h>
#include <math.h>

#define N_NODES 100000
#define N_RELS 16
#define N_EDGES 1600000
#define OUTW 136   // 64+32+16+16+8
#define NEG_SLOPE 0.01f
#define RES ((size_t)N_NODES * OUTW)

__device__ __forceinline__ float lrelu(float x) { return x >= 0.f ? x : NEG_SLOPE * x; }

__device__ __forceinline__ float fast_rcp(float x) {
#if __has_builtin(__builtin_amdgcn_rcpf)
    return __builtin_amdgcn_rcpf(x);
#else
    return 1.f / x;
#endif
}
// tanh(x) = 1 - 2/(e^{2x}+1); exact limits at +/-inf via rcp(inf)=0, rcp(1)=1
__device__ __forceinline__ float fast_tanh(float x) {
    float e = __expf(2.f * x);
    return 1.f - 2.f * fast_rcp(e + 1.f);
}

// ---------------- CSR offsets over sorted dst ----------------
__global__ void k_offsets(const int* __restrict__ dst, int* __restrict__ offs) {
    int n = blockIdx.x * blockDim.x + threadIdx.x;
    if (n > N_NODES) return;
    int lo = 0, hi = N_EDGES;
    while (lo < hi) {
        int mid = (lo + hi) >> 1;
        if (dst[mid] < n) lo = mid + 1; else hi = mid;
    }
    offs[n] = lo;
}

// ---------------- etype bucketing: zero / hist / scan / scatter ----------------
__global__ void k_zero(int* __restrict__ cnt) {
    if (threadIdx.x < 16) cnt[threadIdx.x] = 0;
}

__global__ __launch_bounds__(256) void k_hist(const int* __restrict__ etype, int* __restrict__ cnt) {
    __shared__ int lcnt[16];
    int tid = threadIdx.x;
    if (tid < 16) lcnt[tid] = 0;
    __syncthreads();
    int e = blockIdx.x * 256 + tid;
    atomicAdd(&lcnt[etype[e]], 1);
    __syncthreads();
    if (tid < 16 && lcnt[tid]) atomicAdd(&cnt[tid], lcnt[tid]);
}

__global__ void k_scan(const int* __restrict__ cnt, int* __restrict__ roff, int* __restrict__ cur) {
    if (threadIdx.x == 0) {
        int a = 0;
        for (int r = 0; r < 16; ++r) { roff[r] = a; cur[r] = a; a += cnt[r]; }
        roff[16] = a;
    }
}

__global__ __launch_bounds__(256) void k_scatter(const int* __restrict__ etype,
                                                 int* __restrict__ cur, int* __restrict__ eperm) {
    __shared__ int lcnt[16], lbase[16], loff[16];
    int tid = threadIdx.x;
    if (tid < 16) { lcnt[tid] = 0; loff[tid] = 0; }
    __syncthreads();
    int e = blockIdx.x * 256 + tid;
    int t = etype[e];
    atomicAdd(&lcnt[t], 1);
    __syncthreads();
    if (tid < 16) lbase[tid] = lcnt[tid] ? atomicAdd(&cur[tid], lcnt[tid]) : 0;
    __syncthreads();
    int rank = atomicAdd(&loff[t], 1);
    eperm[lbase[t] + rank] = e;
}

// ---------------- per-relation GEMM  buf = emb @ W_R[r]  (N x 64)(64 x 64) ----------------
#define GM 128
__global__ __launch_bounds__(256) void k_gemm_rel(const float* __restrict__ A,
                                                  const float* __restrict__ W,
                                                  float* __restrict__ C) {
    __shared__ float AsT[64][GM + 4];
    __shared__ float Ws[64][68];
    const int tid = threadIdx.x;
    const size_t row0 = (size_t)blockIdx.x * GM;

    for (int i = 0; i < 8; ++i) {
        int v = i * 256 + tid;
        int r = v >> 4, kc = (v & 15) * 4;
        size_t gr = row0 + r;
        float4 a = (gr < N_NODES) ? *(const float4*)(A + gr * 64 + kc)
                                  : make_float4(0.f, 0.f, 0.f, 0.f);
        AsT[kc + 0][r] = a.x; AsT[kc + 1][r] = a.y;
        AsT[kc + 2][r] = a.z; AsT[kc + 3][r] = a.w;
    }
    for (int i = 0; i < 4; ++i) {
        int v = i * 256 + tid;
        int r = v >> 4, c = (v & 15) * 4;
        float4 w = *(const float4*)(W + (size_t)v * 4);
        Ws[r][c + 0] = w.x; Ws[r][c + 1] = w.y; Ws[r][c + 2] = w.z; Ws[r][c + 3] = w.w;
    }
    __syncthreads();

    const int rg = tid >> 4, cg = tid & 15;
    const int r0 = rg * 8, c0 = cg * 4;
    float acc[8][4] = {};
    #pragma unroll 4
    for (int k = 0; k < 64; ++k) {
        float4 a0 = *(float4*)&AsT[k][r0];
        float4 a1 = *(float4*)&AsT[k][r0 + 4];
        float4 b  = *(float4*)&Ws[k][c0];
        float av[8] = {a0.x, a0.y, a0.z, a0.w, a1.x, a1.y, a1.z, a1.w};
        float bv[4] = {b.x, b.y, b.z, b.w};
        #pragma unroll
        for (int i = 0; i < 8; ++i)
            #pragma unroll
            for (int j = 0; j < 4; ++j) acc[i][j] += av[i] * bv[j];
    }
    for (int i = 0; i < 8; ++i) {
        size_t gr = row0 + r0 + i;
        if (gr < N_NODES)
            *(float4*)(C + gr * 64 + c0) = make_float4(acc[i][0], acc[i][1], acc[i][2], acc[i][3]);
    }
}

// ---------------- bucketed attention: 4 edges/wave, 16 lanes x float4 per edge ----------------
__global__ __launch_bounds__(256) void k_edge_att2(const float* __restrict__ buf,
                                                   const float* __restrict__ rel,
                                                   const int* __restrict__ src,
                                                   const int* __restrict__ dstv,
                                                   const int* __restrict__ eperm,
                                                   const int* __restrict__ roff,
                                                   int r, float* __restrict__ att) {
    __shared__ float rl[64];
    int tid = threadIdx.x;
    if (tid < 64) rl[tid] = rel[tid];
    __syncthreads();
    int lo = roff[r], cnt = roff[r + 1] - lo;
    int lane = tid & 63;
    int slot = lane >> 4;
    int d0 = (lane & 15) * 4;
    int waveglob = (blockIdx.x * 256 + tid) >> 6;
    int nwaves = (gridDim.x * 256) >> 6;
    float4 rr = *(const float4*)&rl[d0];
    for (int i = waveglob * 4 + slot; i < cnt; i += nwaves * 4) {
        int e = eperm[lo + i];
        long s = src[e], dn = dstv[e];
        float4 t = *(const float4*)(buf + s * 64 + d0);
        float4 h = *(const float4*)(buf + dn * 64 + d0);
        float v = t.x * fast_tanh(h.x + rr.x) + t.y * fast_tanh(h.y + rr.y)
                + t.z * fast_tanh(h.z + rr.z) + t.w * fast_tanh(h.w + rr.w);
        #pragma unroll
        for (int m = 1; m < 16; m <<= 1) v += __shfl_xor(v, m);
        if ((lane & 15) == 0) att[e] = v;
    }
}

// ---------------- per-dst-node softmax (in place) ----------------
__global__ void k_softmax(float* __restrict__ att, const int* __restrict__ offs) {
    int n = blockIdx.x * blockDim.x + threadIdx.x;
    if (n >= N_NODES) return;
    int b = offs[n], ee = offs[n + 1];
    if (b >= ee) return;
    float m = -INFINITY;
    for (int e = b; e < ee; ++e) m = fmaxf(m, att[e]);
    float s = 0.f;
    for (int e = b; e < ee; ++e) { float v = __expf(att[e] - m); att[e] = v; s += v; }
    float inv = fast_rcp(s);
    for (int e = b; e < ee; ++e) att[e] *= inv;
}

// ---------------- fused: aggregate + (x+Nh)@W+b, lrelu, write unnorm + normalized ----------------
__global__ __launch_bounds__(256) void k_agg_layer(const float* __restrict__ x,
                                                   const float* __restrict__ att,
                                                   const int* __restrict__ src,
                                                   const int* __restrict__ offs,
                                                   const float* __restrict__ W,
                                                   const float* __restrict__ bias,
                                                   int din, int dout,
                                                   float* __restrict__ Unext,
                                                   float* __restrict__ out, int col, int rstart) {
    extern __shared__ float sh[];      // din*dout + dout + 4*din
    float* Wl = sh;
    float* bl = sh + din * dout;
    float* xm = bl + dout;
    int tid = threadIdx.x;
    for (int v = tid; v < din * dout; v += 256) Wl[v] = W[v];
    if (tid < dout) bl[tid] = bias[tid];
    __syncthreads();

    int w = tid >> 6, lane = tid & 63;
    int n = blockIdx.x * 4 + w;        // grid is exact: 25000*4 == N_NODES
    int b = offs[n], e = offs[n + 1];
    if (lane < din) {
        const float* xe = x + lane;
        float acc = 0.f;
        int i = b;
        for (; i + 4 <= e; i += 4) {
            float a0 = att[i], a1 = att[i + 1], a2 = att[i + 2], a3 = att[i + 3];
            long s0 = src[i], s1 = src[i + 1], s2 = src[i + 2], s3 = src[i + 3];
            float g0 = xe[s0 * din], g1 = xe[s1 * din], g2 = xe[s2 * din], g3 = xe[s3 * din];
            acc += a0 * g0; acc += a1 * g1; acc += a2 * g2; acc += a3 * g3;
        }
        for (; i < e; ++i) acc += att[i] * xe[(long)src[i] * din];
        xm[w * din + lane] = x[(size_t)n * din + lane] + acc;
    }
    __syncthreads();

    float u = 0.f;
    if (lane < dout) {
        float o = bl[lane];
        const float* xv = xm + w * din;
        for (int k = 0; k < din; ++k) o += xv[k] * Wl[k * dout + lane];
        u = lrelu(o);
        if (Unext) Unext[(size_t)n * dout + lane] = u;
    }
    float ss = u * u;
    #pragma unroll
    for (int m = 16; m >= 1; m >>= 1) if (m < dout) ss += __shfl_xor(ss, m);
    ss += __shfl_xor(ss, dout >> 1);   // ensure full dout-group reduce (dout is pow2 <= 32)
    // The two lines above double-count; do the reduction cleanly instead:
    // (recompute from scratch)
    ss = u * u;
    for (int m = dout >> 1; m >= 1; m >>= 1) ss += __shfl_xor(ss, m);
    if (lane < dout) {
        float nrm = u * fast_rcp(fmaxf(sqrtf(ss), 1e-12f));
        for (int rr = rstart; rr < 4; ++rr)
            out[(size_t)rr * RES + (size_t)n * OUTW + col + lane] = nrm;
    }
}

// ---------------- plain linear layer + lrelu + norm (B-chains) ----------------
__global__ __launch_bounds__(256) void k_layer_norm(const float* __restrict__ x,
                                                    const float* __restrict__ W,
                                                    const float* __restrict__ bias,
                                                    int din, int dout,
                                                    float* __restrict__ Unext,
                                                    float* __restrict__ out, int col, int ridx) {
    extern __shared__ float sh[];      // din*dout + dout
    float* Wl = sh;
    float* bl = sh + din * dout;
    int tid = threadIdx.x;
    for (int v = tid; v < din * dout; v += 256) Wl[v] = W[v];
    if (tid < dout) bl[tid] = bias[tid];
    __syncthreads();
    int npb = 256 / dout;
    int j = tid % dout;
    int n = blockIdx.x * npb + tid / dout;   // grids exact for dout in {8,16,32}
    const float* xr = x + (size_t)n * din;
    float o = bl[j];
    for (int k = 0; k < din; ++k) o += xr[k] * Wl[k * dout + j];
    float u = lrelu(o);
    if (Unext) Unext[(size_t)n * dout + j] = u;
    float ss = u * u;
    for (int m = dout >> 1; m >= 1; m >>= 1) ss += __shfl_xor(ss, m);
    float nrm = u * fast_rcp(fmaxf(sqrtf(ss), 1e-12f));
    out[(size_t)ridx * RES + (size_t)n * OUTW + col + j] = nrm;
}

// ---------------- emb block copy to all 4 results ----------------
__global__ __launch_bounds__(256) void k_emb_copy(const float* __restrict__ emb,
                                                  float* __restrict__ out) {
    int idx = blockIdx.x * 256 + threadIdx.x;   // N*16 float4 slots
    int n = idx >> 4, c = (idx & 15) * 4;
    float4 v = *(const float4*)(emb + (size_t)n * 64 + c);
    #pragma unroll
    for (int r = 0; r < 4; ++r)
        *(float4*)(out + (size_t)r * RES + (size_t)n * OUTW + c) = v;
}

extern "C" void kernel_launch(void* const* d_in, const int* in_sizes, int n_in,
                              void* d_out, int out_size, void* d_ws, size_t ws_size,
                              hipStream_t stream) {
    (void)in_sizes; (void)n_in; (void)out_size; (void)ws_size;
    const float* emb = (const float*)d_in[0];
    const float* rel_embed = (const float*)d_in[1];
    const float* W_R = (const float*)d_in[2];
    const float* W0 = (const float*)d_in[3];  const float* b0 = (const float*)d_in[4];
    const float* W1 = (const float*)d_in[5];  const float* b1 = (const float*)d_in[6];
    const float* W2 = (const float*)d_in[7];  const float* b2 = (const float*)d_in[8];
    const float* W3 = (const float*)d_in[9];  const float* b3 = (const float*)d_in[10];
    const int* src = (const int*)d_in[11];
    const int* dst = (const int*)d_in[12];
    const int* etype = (const int*)d_in[13];
    float* out = (float*)d_out;

    char* p = (char*)d_ws;
    auto alloc = [&](size_t bytes) { char* q = p; p += (bytes + 255) & ~(size_t)255; return q; };
    int* offs    = (int*)alloc((size_t)(N_NODES + 1) * 4);
    float* att   = (float*)alloc((size_t)N_EDGES * 4);
    int* eperm   = (int*)alloc((size_t)N_EDGES * 4);
    int* cnt     = (int*)alloc(64);
    int* roff    = (int*)alloc(68);
    int* cur     = (int*)alloc(64);
    float* buf   = (float*)alloc((size_t)N_NODES * 64 * 4);  // relation transform; B-scratch later
    float* U1    = (float*)alloc((size_t)N_NODES * 32 * 4);
    float* U2    = (float*)alloc((size_t)N_NODES * 16 * 4);
    float* U3    = (float*)alloc((size_t)N_NODES * 16 * 4);
    float* B12u  = buf;                                       // reuse buf after attention phase
    float* B13u  = buf + (size_t)N_NODES * 16;
    float* B23u  = buf + (size_t)N_NODES * 32;

    // CSR offsets + etype buckets
    k_offsets<<<(N_NODES + 256) / 256, 256, 0, stream>>>(dst, offs);
    k_zero<<<1, 64, 0, stream>>>(cnt);
    k_hist<<<N_EDGES / 256, 256, 0, stream>>>(etype, cnt);
    k_scan<<<1, 64, 0, stream>>>(cnt, roff, cur);
    k_scatter<<<N_EDGES / 256, 256, 0, stream>>>(etype, cur, eperm);

    // attention scores, relation by relation
    for (int r = 0; r < N_RELS; ++r) {
        k_gemm_rel<<<(N_NODES + GM - 1) / GM, 256, 0, stream>>>(emb, W_R + (size_t)r * 64 * 64, buf);
        k_edge_att2<<<1024, 256, 0, stream>>>(buf, rel_embed + (size_t)r * 64, src, dst,
                                              eperm, roff, r, att);
    }
    k_softmax<<<(N_NODES + 255) / 256, 256, 0, stream>>>(att, offs);

    // A-chain: fused aggregate+layer+norm-broadcast
    k_agg_layer<<<N_NODES / 4, 256, (64 * 32 + 32 + 4 * 64) * 4, stream>>>(
        emb, att, src, offs, W0, b0, 64, 32, U1, out, 64, 0);
    k_agg_layer<<<N_NODES / 4, 256, (32 * 16 + 16 + 4 * 32) * 4, stream>>>(
        U1, att, src, offs, W1, b1, 32, 16, U2, out, 96, 1);
    k_agg_layer<<<N_NODES / 4, 256, (16 * 16 + 16 + 4 * 16) * 4, stream>>>(
        U2, att, src, offs, W2, b2, 16, 16, U3, out, 112, 2);
    k_agg_layer<<<N_NODES / 4, 256, (16 * 8 + 8 + 4 * 16) * 4, stream>>>(
        U3, att, src, offs, W3, b3, 16, 8, nullptr, out, 128, 3);

    // B-chains: linear + norm
    k_layer_norm<<<N_NODES * 16 / 256, 256, (32 * 16 + 16) * 4, stream>>>(U1,   W1, b1, 32, 16, B12u, out, 96, 0);
    k_layer_norm<<<N_NODES * 16 / 256, 256, (16 * 16 + 16) * 4, stream>>>(B12u, W2, b2, 16, 16, B13u, out, 112, 0);
    k_layer_norm<<<N_NODES *  8 / 256, 256, (16 * 8 + 8) * 4,  stream>>>(B13u, W3, b3, 16, 8, nullptr, out, 128, 0);
    k_layer_norm<<<N_NODES * 16 / 256, 256, (16 * 16 + 16) * 4, stream>>>(U2,   W2, b2, 16, 16, B23u, out, 112, 1);
    k_layer_norm<<<N_NODES *  8 / 256, 256, (16 * 8 + 8) * 4,  stream>>>(B23u, W3, b3, 16, 8, nullptr, out, 128, 1);
    k_layer_norm<<<N_NODES *  8 / 256, 256, (16 * 8 + 8) * 4,  stream>>>(U3,   W3, b3, 16, 8, nullptr, out, 128, 2);

    // emb block to all results
    k_emb_copy<<<N_NODES * 16 / 256, 256, 0, stream>>>(emb, out);
}

// Round 4
// 844.734 us; speedup vs baseline: 3.5136x; 1.3610x over previous
//
#include <hip/hip_runtime.h>
#include <hip/hip_bf16.h>
#include <math.h>

#define N_NODES 100000
#define N_RELS 16
#define N_EDGES 1600000
#define OUTW 136   // 64+32+16+16+8
#define NEG_SLOPE 0.01f
#define RES ((size_t)N_NODES * OUTW)

typedef __attribute__((ext_vector_type(8))) short short8;   // 8 bf16 (4 VGPR)
typedef __attribute__((ext_vector_type(4))) float f32x4;

__device__ __forceinline__ float lrelu(float x) { return x >= 0.f ? x : NEG_SLOPE * x; }
__device__ __forceinline__ float fast_rcp(float x) { return __builtin_amdgcn_rcpf(x); }
__device__ __forceinline__ float fast_tanh(float x) {
    float e = __expf(2.f * x);
    return 1.f - 2.f * fast_rcp(e + 1.f);
}
__device__ __forceinline__ float bf1(unsigned short u) { union { unsigned u; float f; } v; v.u = ((unsigned)u) << 16; return v.f; }
__device__ __forceinline__ unsigned short f2bf(float f) {
    union { float f; unsigned u; } v; v.f = f;
    unsigned x = v.u + 0x7FFF + ((v.u >> 16) & 1);
    return (unsigned short)(x >> 16);
}

// ---------------- CSR offsets over sorted dst ----------------
__global__ void k_offsets(const int* __restrict__ dst, int* __restrict__ offs) {
    int n = blockIdx.x * blockDim.x + threadIdx.x;
    if (n > N_NODES) return;
    int lo = 0, hi = N_EDGES;
    while (lo < hi) { int mid = (lo + hi) >> 1; if (dst[mid] < n) lo = mid + 1; else hi = mid; }
    offs[n] = lo;
}

// ---------------- etype bucketing ----------------
__global__ void k_zero(int* __restrict__ cnt) { if (threadIdx.x < 16) cnt[threadIdx.x] = 0; }

__global__ __launch_bounds__(256) void k_hist(const int* __restrict__ etype, int* __restrict__ cnt) {
    __shared__ int lcnt[16];
    int tid = threadIdx.x;
    if (tid < 16) lcnt[tid] = 0;
    __syncthreads();
    atomicAdd(&lcnt[etype[blockIdx.x * 256 + tid]], 1);
    __syncthreads();
    if (tid < 16 && lcnt[tid]) atomicAdd(&cnt[tid], lcnt[tid]);
}

__global__ void k_scan(const int* __restrict__ cnt, int* __restrict__ roff, int* __restrict__ cur) {
    if (threadIdx.x == 0) {
        int a = 0;
        for (int r = 0; r < 16; ++r) { roff[r] = a; cur[r] = a; a += cnt[r]; }
        roff[16] = a;
    }
}

__global__ __launch_bounds__(256) void k_scatter(const int* __restrict__ etype,
                                                 int* __restrict__ cur, int* __restrict__ eperm) {
    __shared__ int lcnt[16], lbase[16], loff[16];
    int tid = threadIdx.x;
    if (tid < 16) { lcnt[tid] = 0; loff[tid] = 0; }
    __syncthreads();
    int e = blockIdx.x * 256 + tid;
    int t = etype[e];
    atomicAdd(&lcnt[t], 1);
    __syncthreads();
    if (tid < 16) lbase[tid] = lcnt[tid] ? atomicAdd(&cur[tid], lcnt[tid]) : 0;
    __syncthreads();
    int rank = atomicAdd(&loff[t], 1);
    eperm[lbase[t] + rank] = e;
}

// ---------------- precasts ----------------
__global__ __launch_bounds__(256) void k_cast_emb(const float* __restrict__ emb, unsigned short* __restrict__ embB) {
    int id = blockIdx.x * 256 + threadIdx.x;          // 1.6M float4 slots
    float4 v = *(const float4*)(emb + (size_t)id * 4);
    ushort4 o; o.x = f2bf(v.x); o.y = f2bf(v.y); o.z = f2bf(v.z); o.w = f2bf(v.w);
    *(ushort4*)(embB + (size_t)id * 4) = o;
}

// W_R[r][k][n] fp32 -> WT[r][n][k] bf16
__global__ __launch_bounds__(256) void k_prep_wr(const float* __restrict__ WR, unsigned short* __restrict__ WT) {
    int id = blockIdx.x * 256 + threadIdx.x;          // 65536
    int r = id >> 12, rem = id & 4095, n = rem >> 6, k = rem & 63;
    WT[id] = f2bf(WR[(r << 12) + (k << 6) + n]);
}

// layer weights -> fp32 transposed [c][k]; offsets: L0@0(32x64) L1@2048(16x32) L2@2560(16x16) L3@2816(8x16)
__global__ __launch_bounds__(256) void k_prep_wl(const float* __restrict__ W0, const float* __restrict__ W1,
                                                 const float* __restrict__ W2, const float* __restrict__ W3,
                                                 float* __restrict__ WLT) {
    int id = blockIdx.x * 256 + threadIdx.x;
    if (id >= 2944) return;
    float v;
    if (id < 2048)      { int c = id >> 6, k = id & 63;                  v = W0[k * 32 + c]; }
    else if (id < 2560) { int r = id - 2048; int c = r >> 5, k = r & 31; v = W1[k * 16 + c]; }
    else if (id < 2816) { int r = id - 2560; int c = r >> 4, k = r & 15; v = W2[k * 16 + c]; }
    else                { int r = id - 2816; int c = r >> 4, k = r & 15; v = W3[k * 8 + c]; }
    WLT[id] = v;
}

// ---------------- MFMA GEMM: bufs[cr] = embB @ W_R[c0+cr]  (bf16 in, bf16 out for gathers) ----------------
__global__ __launch_bounds__(256) void k_gemm_mfma(const unsigned short* __restrict__ embB,
                                                   const unsigned short* __restrict__ WT,   // pre-offset by c0
                                                   unsigned short* __restrict__ bufs, int nrel) {
    int tid = threadIdx.x, w = tid >> 6, l = tid & 63;
    int row0 = blockIdx.x * 128 + w * 32;
    int rlo = l & 15, rhi = l >> 4;

    short8 a[2][2];
    #pragma unroll
    for (int rb = 0; rb < 2; ++rb)
        #pragma unroll
        for (int ks = 0; ks < 2; ++ks) {
            int r = row0 + rb * 16 + rlo;
            if (r >= N_NODES) r = N_NODES - 1;
            a[rb][ks] = *(const short8*)(embB + (size_t)r * 64 + ks * 32 + rhi * 8);
        }

    for (int cr = 0; cr < nrel; ++cr) {
        const unsigned short* wt = WT + ((size_t)cr << 12);
        f32x4 acc[2][4];
        #pragma unroll
        for (int rb = 0; rb < 2; ++rb)
            #pragma unroll
            for (int cb = 0; cb < 4; ++cb) acc[rb][cb] = (f32x4){0.f, 0.f, 0.f, 0.f};
        #pragma unroll
        for (int cb = 0; cb < 4; ++cb) {
            short8 b0 = *(const short8*)(wt + (cb * 16 + rlo) * 64 + rhi * 8);
            short8 b1 = *(const short8*)(wt + (cb * 16 + rlo) * 64 + 32 + rhi * 8);
            acc[0][cb] = __builtin_amdgcn_mfma_f32_16x16x32_bf16(a[0][0], b0, acc[0][cb], 0, 0, 0);
            acc[0][cb] = __builtin_amdgcn_mfma_f32_16x16x32_bf16(a[0][1], b1, acc[0][cb], 0, 0, 0);
            acc[1][cb] = __builtin_amdgcn_mfma_f32_16x16x32_bf16(a[1][0], b0, acc[1][cb], 0, 0, 0);
            acc[1][cb] = __builtin_amdgcn_mfma_f32_16x16x32_bf16(a[1][1], b1, acc[1][cb], 0, 0, 0);
        }
        unsigned short* ob = bufs + (size_t)cr * N_NODES * 64;
        #pragma unroll
        for (int rb = 0; rb < 2; ++rb)
            #pragma unroll
            for (int cb = 0; cb < 4; ++cb)
                #pragma unroll
                for (int i = 0; i < 4; ++i) {
                    int gr = row0 + rb * 16 + rhi * 4 + i;
                    if (gr < N_NODES) ob[(size_t)gr * 64 + cb * 16 + rlo] = f2bf(acc[rb][cb][i]);
                }
    }
}

// ---------------- bucketed attention over chunk [c0, c0+nc) ----------------
__global__ __launch_bounds__(256) void k_edge_att3(const unsigned short* __restrict__ bufs,
                                                   const float* __restrict__ rel,
                                                   const int* __restrict__ src,
                                                   const int* __restrict__ dstv,
                                                   const int* __restrict__ eperm,
                                                   const int* __restrict__ roff,
                                                   const int* __restrict__ etype,
                                                   int c0, int nc, float* __restrict__ att) {
    int lo = roff[c0], cnt = roff[c0 + nc] - lo;
    int tid = threadIdx.x, lane = tid & 63;
    int slot = lane >> 4, lg = lane & 15, d0 = lg * 4;
    int gw = (blockIdx.x * 256 + tid) >> 6;
    int nw = (gridDim.x * 256) >> 6;
    for (int i = gw * 4 + slot; i < cnt; i += nw * 4) {
        int e = eperm[lo + i];
        int t = etype[e];
        const unsigned short* bb = bufs + (size_t)(t - c0) * N_NODES * 64;
        size_t s = (size_t)src[e], dn = (size_t)dstv[e];
        ushort4 tv = *(const ushort4*)(bb + s * 64 + d0);
        ushort4 hv = *(const ushort4*)(bb + dn * 64 + d0);
        float4 rr = *(const float4*)(rel + (size_t)t * 64 + d0);
        float v = bf1(tv.x) * fast_tanh(bf1(hv.x) + rr.x)
                + bf1(tv.y) * fast_tanh(bf1(hv.y) + rr.y)
                + bf1(tv.z) * fast_tanh(bf1(hv.z) + rr.z)
                + bf1(tv.w) * fast_tanh(bf1(hv.w) + rr.w);
        #pragma unroll
        for (int m = 1; m < 16; m <<= 1) v += __shfl_xor(v, m);
        if (lg == 0) att[e] = v;
    }
}

// ---------------- per-dst softmax, 8 lanes per node ----------------
__global__ __launch_bounds__(256) void k_softmax(float* __restrict__ att, const int* __restrict__ offs) {
    int tid = threadIdx.x;
    int n = blockIdx.x * 32 + (tid >> 3);
    int j = tid & 7;
    int b = offs[n], e = offs[n + 1];
    if (b >= e) return;
    float m = -INFINITY;
    for (int i = b + j; i < e; i += 8) m = fmaxf(m, att[i]);
    #pragma unroll
    for (int s = 4; s >= 1; s >>= 1) m = fmaxf(m, __shfl_xor(m, s));
    float sum = 0.f;
    for (int i = b + j; i < e; i += 8) { float v = __expf(att[i] - m); att[i] = v; sum += v; }
    #pragma unroll
    for (int s = 4; s >= 1; s >>= 1) sum += __shfl_xor(sum, s);
    float inv = fast_rcp(sum);
    for (int i = b + j; i < e; i += 8) att[i] *= inv;
}

// ---------------- fused aggregate + layer + norm-broadcast (fp32 chain) ----------------
// x fp32 [N][DIN]; WLT fp32 [DOUT][DIN] (c-major)
template<int DIN, int DOUT, int COL, int RSTART, bool WU>
__global__ __launch_bounds__(256) void k_agg(const float* __restrict__ x,
                                             const float* __restrict__ att,
                                             const int* __restrict__ src,
                                             const int* __restrict__ offs,
                                             const float* __restrict__ WLT,
                                             const float* __restrict__ bias,
                                             float* __restrict__ Un,
                                             float* __restrict__ out) {
    constexpr int L = DIN / 2;        // lanes per edge (float2 each)
    constexpr int S = 64 / L;         // edge slots per wave
    constexpr int G = 64 / DOUT;      // k-groups for matmul
    constexpr int KS = DIN / G;       // k-slice per lane
    __shared__ float xm[4][DIN];
    int tid = threadIdx.x, w = tid >> 6, l = tid & 63;
    int n = blockIdx.x * 4 + w;
    int b = offs[n], e = offs[n + 1];
    int j = l & (L - 1), slot = l / L;
    int c = l & (DOUT - 1), g = l / DOUT;

    float Wreg[KS];
    #pragma unroll
    for (int kk = 0; kk < KS; ++kk) Wreg[kk] = WLT[(size_t)c * DIN + g * KS + kk];

    float ax = 0.f, ay = 0.f;
    int i = b + slot;
    for (; i + S < e; i += 2 * S) {
        float a0 = att[i], a1 = att[i + S];
        float2 p0 = *(const float2*)(x + (size_t)src[i] * DIN + 2 * j);
        float2 p1 = *(const float2*)(x + (size_t)src[i + S] * DIN + 2 * j);
        ax += a0 * p0.x + a1 * p1.x;
        ay += a0 * p0.y + a1 * p1.y;
    }
    for (; i < e; i += S) {
        float a0 = att[i];
        float2 p0 = *(const float2*)(x + (size_t)src[i] * DIN + 2 * j);
        ax += a0 * p0.x; ay += a0 * p0.y;
    }
    #pragma unroll
    for (int st = L; st < 64; st <<= 1) { ax += __shfl_xor(ax, st); ay += __shfl_xor(ay, st); }
    if (l < L) {
        float2 q = *(const float2*)(x + (size_t)n * DIN + 2 * j);
        *(float2*)&xm[w][2 * j] = make_float2(ax + q.x, ay + q.y);
    }
    __builtin_amdgcn_s_waitcnt(0);   // drain wave-local LDS writes (xm is per-wave)

    float o = 0.f;
    if constexpr (KS >= 4) {
        #pragma unroll
        for (int kk = 0; kk < KS; kk += 4) {
            float4 xv = *(const float4*)&xm[w][g * KS + kk];
            o += xv.x * Wreg[kk] + xv.y * Wreg[kk + 1] + xv.z * Wreg[kk + 2] + xv.w * Wreg[kk + 3];
        }
    } else {
        float2 xv = *(const float2*)&xm[w][g * KS];
        o += xv.x * Wreg[0] + xv.y * Wreg[1];
    }
    #pragma unroll
    for (int st = DOUT; st < 64; st <<= 1) o += __shfl_xor(o, st);

    float u = 0.f;
    if (l < DOUT) {
        u = lrelu(o + bias[l]);
        if (WU) Un[(size_t)n * DOUT + l] = u;
    }
    float ss = u * u;
    #pragma unroll
    for (int m = DOUT / 2; m >= 1; m >>= 1) ss += __shfl_xor(ss, m);
    if (l < DOUT) {
        float nrm = u * fast_rcp(fmaxf(sqrtf(ss), 1e-12f));
        #pragma unroll
        for (int rr = RSTART; rr < 4; ++rr)
            out[(size_t)rr * RES + (size_t)n * OUTW + COL + l] = nrm;
    }
}

// ---------------- plain linear + lrelu + norm (B-chains, fp32) ----------------
template<int DIN, int DOUT, int COL, int RIDX, bool WU>
__global__ __launch_bounds__(256) void k_layer_norm(const float* __restrict__ x,
                                                    const float* __restrict__ WLT,
                                                    const float* __restrict__ bias,
                                                    float* __restrict__ Un,
                                                    float* __restrict__ out) {
    int tid = threadIdx.x;
    int j = tid & (DOUT - 1);
    int n = blockIdx.x * (256 / DOUT) + tid / DOUT;
    const float* xr = x + (size_t)n * DIN;
    const float* wr = WLT + (size_t)j * DIN;
    float o = bias[j];
    #pragma unroll
    for (int k = 0; k < DIN; k += 4) {
        float4 xv = *(const float4*)(xr + k);
        float4 wv = *(const float4*)(wr + k);
        o += xv.x * wv.x + xv.y * wv.y + xv.z * wv.z + xv.w * wv.w;
    }
    float u = lrelu(o);
    if (WU) Un[(size_t)n * DOUT + j] = u;
    float ss = u * u;
    #pragma unroll
    for (int m = DOUT / 2; m >= 1; m >>= 1) ss += __shfl_xor(ss, m);
    float nrm = u * fast_rcp(fmaxf(sqrtf(ss), 1e-12f));
    out[(size_t)RIDX * RES + (size_t)n * OUTW + COL + j] = nrm;
}

// ---------------- emb block copy to all 4 results ----------------
__global__ __launch_bounds__(256) void k_emb_copy(const float* __restrict__ emb, float* __restrict__ out) {
    int idx = blockIdx.x * 256 + threadIdx.x;
    int n = idx >> 4, cc = (idx & 15) * 4;
    float4 v = *(const float4*)(emb + (size_t)n * 64 + cc);
    #pragma unroll
    for (int r = 0; r < 4; ++r)
        *(float4*)(out + (size_t)r * RES + (size_t)n * OUTW + cc) = v;
}

extern "C" void kernel_launch(void* const* d_in, const int* in_sizes, int n_in,
                              void* d_out, int out_size, void* d_ws, size_t ws_size,
                              hipStream_t stream) {
    (void)in_sizes; (void)n_in; (void)out_size;
    const float* emb = (const float*)d_in[0];
    const float* rel_embed = (const float*)d_in[1];
    const float* W_R = (const float*)d_in[2];
    const float* W0 = (const float*)d_in[3];  const float* b0 = (const float*)d_in[4];
    const float* W1 = (const float*)d_in[5];  const float* b1 = (const float*)d_in[6];
    const float* W2 = (const float*)d_in[7];  const float* b2 = (const float*)d_in[8];
    const float* W3 = (const float*)d_in[9];  const float* b3 = (const float*)d_in[10];
    const int* src = (const int*)d_in[11];
    const int* dst = (const int*)d_in[12];
    const int* etype = (const int*)d_in[13];
    float* out = (float*)d_out;

    char* p = (char*)d_ws;
    auto alloc = [&](size_t bytes) { char* q = p; p += (bytes + 255) & ~(size_t)255; return q; };
    int* offs  = (int*)alloc((size_t)(N_NODES + 1) * 4);
    float* att = (float*)alloc((size_t)N_EDGES * 4);
    int* eperm = (int*)alloc((size_t)N_EDGES * 4);
    int* cnt   = (int*)alloc(64);
    int* roff  = (int*)alloc(68);
    int* cur   = (int*)alloc(64);
    unsigned short* embB = (unsigned short*)alloc((size_t)N_NODES * 64 * 2);
    unsigned short* WT   = (unsigned short*)alloc((size_t)65536 * 2);
    float* WLT  = (float*)alloc((size_t)2944 * 4);
    float* U1   = (float*)alloc((size_t)N_NODES * 32 * 4);
    float* U2   = (float*)alloc((size_t)N_NODES * 16 * 4);
    float* U3   = (float*)alloc((size_t)N_NODES * 16 * 4);
    float* B12u = (float*)alloc((size_t)N_NODES * 16 * 4);
    float* B13u = (float*)alloc((size_t)N_NODES * 16 * 4);
    float* B23u = (float*)alloc((size_t)N_NODES * 16 * 4);
    size_t fixed = (size_t)(p - (char*)d_ws);
    size_t per_rel = (size_t)N_NODES * 64 * 2;   // bf16 buf per relation
    int chunk = 1;
    if (ws_size > fixed + per_rel)
        chunk = (int)((ws_size - fixed) / per_rel);
    if (chunk > 16) chunk = 16;
    if (chunk < 1) chunk = 1;
    unsigned short* allbuf = (unsigned short*)p;

    // prep
    k_offsets<<<(N_NODES + 256) / 256, 256, 0, stream>>>(dst, offs);
    k_zero<<<1, 64, 0, stream>>>(cnt);
    k_hist<<<N_EDGES / 256, 256, 0, stream>>>(etype, cnt);
    k_scan<<<1, 64, 0, stream>>>(cnt, roff, cur);
    k_scatter<<<N_EDGES / 256, 256, 0, stream>>>(etype, cur, eperm);
    k_cast_emb<<<N_NODES * 16 / 256, 256, 0, stream>>>(emb, embB);
    k_prep_wr<<<256, 256, 0, stream>>>(W_R, WT);
    k_prep_wl<<<12, 256, 0, stream>>>(W0, W1, W2, W3, WLT);

    // attention: chunked MFMA transform + edge scores
    for (int c0 = 0; c0 < N_RELS; c0 += chunk) {
        int nc = N_RELS - c0 < chunk ? N_RELS - c0 : chunk;
        k_gemm_mfma<<<(N_NODES + 127) / 128, 256, 0, stream>>>(embB, WT + (size_t)c0 * 4096, allbuf, nc);
        k_edge_att3<<<1024, 256, 0, stream>>>(allbuf, rel_embed, src, dst, eperm, roff, etype, c0, nc, att);
    }
    k_softmax<<<N_NODES / 32, 256, 0, stream>>>(att, offs);

    // A-chain (fused aggregate+layer+norm, broadcast to result rows RSTART..3)
    k_agg<64, 32, 64, 0, true ><<<N_NODES / 4, 256, 0, stream>>>(emb, att, src, offs, WLT,        b0, U1, out);
    k_agg<32, 16, 96, 1, true ><<<N_NODES / 4, 256, 0, stream>>>(U1,  att, src, offs, WLT + 2048, b1, U2, out);
    k_agg<16, 16, 112, 2, true><<<N_NODES / 4, 256, 0, stream>>>(U2,  att, src, offs, WLT + 2560, b2, U3, out);
    k_agg<16, 8, 128, 3, false><<<N_NODES / 4, 256, 0, stream>>>(U3,  att, src, offs, WLT + 2816, b3, nullptr, out);

    // B-chains
    k_layer_norm<32, 16, 96, 0, true ><<<N_NODES * 16 / 256, 256, 0, stream>>>(U1,   WLT + 2048, b1, B12u, out);
    k_layer_norm<16, 16, 112, 0, true><<<N_NODES * 16 / 256, 256, 0, stream>>>(B12u, WLT + 2560, b2, B13u, out);
    k_layer_norm<16, 8, 128, 0, false><<<N_NODES * 8 / 256, 256, 0, stream>>>(B13u, WLT + 2816, b3, nullptr, out);
    k_layer_norm<16, 16, 112, 1, true><<<N_NODES * 16 / 256, 256, 0, stream>>>(U2,   WLT + 2560, b2, B23u, out);
    k_layer_norm<16, 8, 128, 1, false><<<N_NODES * 8 / 256, 256, 0, stream>>>(B23u, WLT + 2816, b3, nullptr, out);
    k_layer_norm<16, 8, 128, 2, false><<<N_NODES * 8 / 256, 256, 0, stream>>>(U3,   WLT + 2816, b3, nullptr, out);

    // emb block
    k_emb_copy<<<N_NODES * 16 / 256, 256, 0, stream>>>(emb, out);
}

// Round 5
// 725.997 us; speedup vs baseline: 4.0882x; 1.1635x over previous
//
#include <hip/hip_runtime.h>
#include <hip/hip_bf16.h>
#include <math.h>

#define N_NODES 100000
#define N_RELS 16
#define N_EDGES 1600000
#define OUTW 136   // 64+32+16+16+8
#define NEG_SLOPE 0.01f
#define RES ((size_t)N_NODES * OUTW)

typedef __attribute__((ext_vector_type(8))) short short8;           // 8 bf16 (4 VGPR)
typedef __attribute__((ext_vector_type(8))) unsigned short ushort8;
typedef __attribute__((ext_vector_type(4))) float f32x4;

__device__ __forceinline__ float lrelu(float x) { return x >= 0.f ? x : NEG_SLOPE * x; }
__device__ __forceinline__ float fast_rcp(float x) { return __builtin_amdgcn_rcpf(x); }
__device__ __forceinline__ float fast_tanh(float x) {
    float e = __expf(2.f * x);
    return 1.f - 2.f * fast_rcp(e + 1.f);
}
__device__ __forceinline__ float bf1(unsigned short u) { union { unsigned u; float f; } v; v.u = ((unsigned)u) << 16; return v.f; }
__device__ __forceinline__ unsigned short f2bf(float f) {
    union { float f; unsigned u; } v; v.f = f;
    unsigned x = v.u + 0x7FFF + ((v.u >> 16) & 1);
    return (unsigned short)(x >> 16);
}

// ---------------- CSR offsets over sorted dst ----------------
__global__ void k_offsets(const int* __restrict__ dst, int* __restrict__ offs) {
    int n = blockIdx.x * blockDim.x + threadIdx.x;
    if (n > N_NODES) return;
    int lo = 0, hi = N_EDGES;
    while (lo < hi) { int mid = (lo + hi) >> 1; if (dst[mid] < n) lo = mid + 1; else hi = mid; }
    offs[n] = lo;
}

// ---------------- etype bucketing ----------------
__global__ void k_zero(int* __restrict__ cnt) { if (threadIdx.x < 16) cnt[threadIdx.x] = 0; }

__global__ __launch_bounds__(256) void k_hist(const int* __restrict__ etype, int* __restrict__ cnt) {
    __shared__ int lcnt[16];
    int tid = threadIdx.x;
    if (tid < 16) lcnt[tid] = 0;
    __syncthreads();
    atomicAdd(&lcnt[etype[blockIdx.x * 256 + tid]], 1);
    __syncthreads();
    if (tid < 16 && lcnt[tid]) atomicAdd(&cnt[tid], lcnt[tid]);
}

__global__ void k_scan(const int* __restrict__ cnt, int* __restrict__ roff, int* __restrict__ cur) {
    if (threadIdx.x == 0) {
        int a = 0;
        for (int r = 0; r < 16; ++r) { roff[r] = a; cur[r] = a; a += cnt[r]; }
        roff[16] = a;
    }
}

// scatter edge ids AND permuted src/dst copies (contiguous reads in the att pass)
__global__ __launch_bounds__(256) void k_scatter(const int* __restrict__ etype,
                                                 const int* __restrict__ src,
                                                 const int* __restrict__ dst,
                                                 int* __restrict__ cur, int* __restrict__ eperm,
                                                 int* __restrict__ srcp, int* __restrict__ dstp) {
    __shared__ int lcnt[16], lbase[16], loff[16];
    int tid = threadIdx.x;
    if (tid < 16) { lcnt[tid] = 0; loff[tid] = 0; }
    __syncthreads();
    int e = blockIdx.x * 256 + tid;
    int t = etype[e];
    atomicAdd(&lcnt[t], 1);
    __syncthreads();
    if (tid < 16) lbase[tid] = lcnt[tid] ? atomicAdd(&cur[tid], lcnt[tid]) : 0;
    __syncthreads();
    int rank = atomicAdd(&loff[t], 1);
    int pos = lbase[t] + rank;
    eperm[pos] = e;
    srcp[pos] = src[e];
    dstp[pos] = dst[e];
}

// ---------------- precasts ----------------
__global__ __launch_bounds__(256) void k_cast_emb(const float* __restrict__ emb, unsigned short* __restrict__ embB) {
    int id = blockIdx.x * 256 + threadIdx.x;          // 1.6M float4 slots
    float4 v = *(const float4*)(emb + (size_t)id * 4);
    ushort4 o; o.x = f2bf(v.x); o.y = f2bf(v.y); o.z = f2bf(v.z); o.w = f2bf(v.w);
    *(ushort4*)(embB + (size_t)id * 4) = o;
}

// W_R[r][k][n] fp32 -> WT[r][n][k] bf16
__global__ __launch_bounds__(256) void k_prep_wr(const float* __restrict__ WR, unsigned short* __restrict__ WT) {
    int id = blockIdx.x * 256 + threadIdx.x;          // 65536
    int r = id >> 12, rem = id & 4095, n = rem >> 6, k = rem & 63;
    WT[id] = f2bf(WR[(r << 12) + (k << 6) + n]);
}

// layer weights fp32 transposed [c][k]; L0@0(32x64) L1@2048(16x32) L2@2560(16x16) L3@2816(8x16)
__global__ __launch_bounds__(256) void k_prep_wl(const float* __restrict__ W0, const float* __restrict__ W1,
                                                 const float* __restrict__ W2, const float* __restrict__ W3,
                                                 float* __restrict__ WLT) {
    int id = blockIdx.x * 256 + threadIdx.x;
    if (id >= 2944) return;
    float v;
    if (id < 2048)      { int c = id >> 6, k = id & 63;                  v = W0[k * 32 + c]; }
    else if (id < 2560) { int r = id - 2048; int c = r >> 5, k = r & 31; v = W1[k * 16 + c]; }
    else if (id < 2816) { int r = id - 2560; int c = r >> 4, k = r & 15; v = W2[k * 16 + c]; }
    else                { int r = id - 2816; int c = r >> 4, k = r & 15; v = W3[k * 8 + c]; }
    WLT[id] = v;
}

// ---------------- MFMA GEMM: bufs[cr] = embB @ W_R[c0+cr]  (bf16 in/out) ----------------
__global__ __launch_bounds__(256) void k_gemm_mfma(const unsigned short* __restrict__ embB,
                                                   const unsigned short* __restrict__ WT,   // pre-offset by c0
                                                   unsigned short* __restrict__ bufs, int nrel) {
    int tid = threadIdx.x, w = tid >> 6, l = tid & 63;
    int row0 = blockIdx.x * 128 + w * 32;
    int rlo = l & 15, rhi = l >> 4;

    short8 a[2][2];
    #pragma unroll
    for (int rb = 0; rb < 2; ++rb)
        #pragma unroll
        for (int ks = 0; ks < 2; ++ks) {
            int r = row0 + rb * 16 + rlo;
            if (r >= N_NODES) r = N_NODES - 1;
            a[rb][ks] = *(const short8*)(embB + (size_t)r * 64 + ks * 32 + rhi * 8);
        }

    for (int cr = 0; cr < nrel; ++cr) {
        const unsigned short* wt = WT + ((size_t)cr << 12);
        f32x4 acc[2][4];
        #pragma unroll
        for (int rb = 0; rb < 2; ++rb)
            #pragma unroll
            for (int cb = 0; cb < 4; ++cb) acc[rb][cb] = (f32x4){0.f, 0.f, 0.f, 0.f};
        #pragma unroll
        for (int cb = 0; cb < 4; ++cb) {
            short8 b0 = *(const short8*)(wt + (cb * 16 + rlo) * 64 + rhi * 8);
            short8 b1 = *(const short8*)(wt + (cb * 16 + rlo) * 64 + 32 + rhi * 8);
            acc[0][cb] = __builtin_amdgcn_mfma_f32_16x16x32_bf16(a[0][0], b0, acc[0][cb], 0, 0, 0);
            acc[0][cb] = __builtin_amdgcn_mfma_f32_16x16x32_bf16(a[0][1], b1, acc[0][cb], 0, 0, 0);
            acc[1][cb] = __builtin_amdgcn_mfma_f32_16x16x32_bf16(a[1][0], b0, acc[1][cb], 0, 0, 0);
            acc[1][cb] = __builtin_amdgcn_mfma_f32_16x16x32_bf16(a[1][1], b1, acc[1][cb], 0, 0, 0);
        }
        unsigned short* ob = bufs + (size_t)cr * N_NODES * 64;
        #pragma unroll
        for (int rb = 0; rb < 2; ++rb)
            #pragma unroll
            for (int cb = 0; cb < 4; ++cb)
                #pragma unroll
                for (int i = 0; i < 4; ++i) {
                    int gr = row0 + rb * 16 + rhi * 4 + i;
                    if (gr < N_NODES) ob[(size_t)gr * 64 + cb * 16 + rlo] = f2bf(acc[rb][cb][i]);
                }
    }
}

// ---------------- attention over chunk [c0, c0+nc): 8 lanes/edge, 8 edges/wave ----------------
__global__ __launch_bounds__(256) void k_edge_att4(const unsigned short* __restrict__ bufs,
                                                   const float* __restrict__ rel,
                                                   const int* __restrict__ srcp,
                                                   const int* __restrict__ dstp,
                                                   const int* __restrict__ eperm,
                                                   const int* __restrict__ roff,
                                                   int c0, int nc, float* __restrict__ att) {
    int lo = roff[c0];
    int cnt = roff[c0 + nc] - lo;
    int bnd0 = (nc > 1) ? roff[c0 + 1] - lo : 0x7fffffff;
    int bnd1 = (nc > 2) ? roff[c0 + 2] - lo : 0x7fffffff;
    int bnd2 = (nc > 3) ? roff[c0 + 3] - lo : 0x7fffffff;
    int tid = threadIdx.x, lane = tid & 63;
    int sub = lane >> 3, lj = lane & 7, d0 = lj * 8;
    int gw = (blockIdx.x * 256 + tid) >> 6;
    int nw = (gridDim.x * 256) >> 6;
    for (int i = gw * 8 + sub; i < cnt; i += nw * 8) {
        int t = (i >= bnd0) + (i >= bnd1) + (i >= bnd2);
        const unsigned short* bb = bufs + (size_t)t * N_NODES * 64;
        const float* rr = rel + (size_t)(c0 + t) * 64 + d0;
        size_t s = (size_t)srcp[lo + i], dn = (size_t)dstp[lo + i];
        ushort8 tv = *(const ushort8*)(bb + s * 64 + d0);
        ushort8 hv = *(const ushort8*)(bb + dn * 64 + d0);
        float4 r0 = *(const float4*)(rr);
        float4 r1 = *(const float4*)(rr + 4);
        float v = bf1(tv[0]) * fast_tanh(bf1(hv[0]) + r0.x)
                + bf1(tv[1]) * fast_tanh(bf1(hv[1]) + r0.y)
                + bf1(tv[2]) * fast_tanh(bf1(hv[2]) + r0.z)
                + bf1(tv[3]) * fast_tanh(bf1(hv[3]) + r0.w)
                + bf1(tv[4]) * fast_tanh(bf1(hv[4]) + r1.x)
                + bf1(tv[5]) * fast_tanh(bf1(hv[5]) + r1.y)
                + bf1(tv[6]) * fast_tanh(bf1(hv[6]) + r1.z)
                + bf1(tv[7]) * fast_tanh(bf1(hv[7]) + r1.w);
        #pragma unroll
        for (int m = 1; m < 8; m <<= 1) v += __shfl_xor(v, m);
        if (lj == 0) att[eperm[lo + i]] = v;
    }
}

// ---------------- per-dst softmax, 8 lanes per node ----------------
__global__ __launch_bounds__(256) void k_softmax(float* __restrict__ att, const int* __restrict__ offs) {
    int tid = threadIdx.x;
    int n = blockIdx.x * 32 + (tid >> 3);
    int j = tid & 7;
    int b = offs[n], e = offs[n + 1];
    if (b >= e) return;
    float m = -INFINITY;
    for (int i = b + j; i < e; i += 8) m = fmaxf(m, att[i]);
    #pragma unroll
    for (int s = 4; s >= 1; s >>= 1) m = fmaxf(m, __shfl_xor(m, s));
    float sum = 0.f;
    for (int i = b + j; i < e; i += 8) { float v = __expf(att[i] - m); att[i] = v; sum += v; }
    #pragma unroll
    for (int s = 4; s >= 1; s >>= 1) sum += __shfl_xor(sum, s);
    float inv = fast_rcp(sum);
    for (int i = b + j; i < e; i += 8) att[i] *= inv;
}

// ---------------- layer-1 fused agg: bf16 gathers from embB, 4 edges/wave ----------------
__global__ __launch_bounds__(256) void k_agg1(const float* __restrict__ emb,
                                              const unsigned short* __restrict__ embB,
                                              const float* __restrict__ att,
                                              const int* __restrict__ src,
                                              const int* __restrict__ offs,
                                              const float* __restrict__ WLT,   // W0T [32][64]
                                              const float* __restrict__ bias,
                                              float* __restrict__ U1,
                                              float* __restrict__ out) {
    __shared__ float xm[4][64];
    int tid = threadIdx.x, w = tid >> 6, l = tid & 63;
    int n = blockIdx.x * 4 + w;
    int b = offs[n], e = offs[n + 1];
    int j = l & 15, slot = l >> 4;      // 16 lanes/edge (4 dims each), 4 edge slots
    int c = l & 31, g = l >> 5;         // matmul mapping

    float Wreg[32];
    #pragma unroll
    for (int kk = 0; kk < 32; ++kk) Wreg[kk] = WLT[(size_t)c * 64 + g * 32 + kk];

    float a0 = 0.f, a1 = 0.f, a2 = 0.f, a3 = 0.f;
    int i = b + slot;
    for (; i + 4 < e; i += 8) {
        float t0 = att[i], t1 = att[i + 4];
        ushort4 p0 = *(const ushort4*)(embB + (size_t)src[i] * 64 + 4 * j);
        ushort4 p1 = *(const ushort4*)(embB + (size_t)src[i + 4] * 64 + 4 * j);
        a0 += t0 * bf1(p0.x) + t1 * bf1(p1.x);
        a1 += t0 * bf1(p0.y) + t1 * bf1(p1.y);
        a2 += t0 * bf1(p0.z) + t1 * bf1(p1.z);
        a3 += t0 * bf1(p0.w) + t1 * bf1(p1.w);
    }
    for (; i < e; i += 4) {
        float t0 = att[i];
        ushort4 p0 = *(const ushort4*)(embB + (size_t)src[i] * 64 + 4 * j);
        a0 += t0 * bf1(p0.x); a1 += t0 * bf1(p0.y); a2 += t0 * bf1(p0.z); a3 += t0 * bf1(p0.w);
    }
    #pragma unroll
    for (int st = 16; st < 64; st <<= 1) {
        a0 += __shfl_xor(a0, st); a1 += __shfl_xor(a1, st);
        a2 += __shfl_xor(a2, st); a3 += __shfl_xor(a3, st);
    }
    if (l < 16) {
        float4 q = *(const float4*)(emb + (size_t)n * 64 + 4 * j);
        *(float4*)&xm[w][4 * j] = make_float4(a0 + q.x, a1 + q.y, a2 + q.z, a3 + q.w);
    }
    __builtin_amdgcn_s_waitcnt(0);
    __builtin_amdgcn_sched_barrier(0);

    float o = 0.f;
    #pragma unroll
    for (int kk = 0; kk < 32; kk += 4) {
        float4 xv = *(const float4*)&xm[w][g * 32 + kk];
        o += xv.x * Wreg[kk] + xv.y * Wreg[kk + 1] + xv.z * Wreg[kk + 2] + xv.w * Wreg[kk + 3];
    }
    o += __shfl_xor(o, 32);

    float u = 0.f;
    if (l < 32) {
        u = lrelu(o + bias[l]);
        U1[(size_t)n * 32 + l] = u;
    }
    float ss = u * u;
    #pragma unroll
    for (int m = 16; m >= 1; m >>= 1) ss += __shfl_xor(ss, m);
    if (l < 32) {
        float nrm = u * fast_rcp(fmaxf(sqrtf(ss), 1e-12f));
        #pragma unroll
        for (int rr = 0; rr < 4; ++rr)
            out[(size_t)rr * RES + (size_t)n * OUTW + 64 + l] = nrm;
    }
}

// ---------------- fused aggregate + layer + norm-broadcast (fp32, U-chain) ----------------
template<int DIN, int DOUT, int COL, int RSTART, bool WU>
__global__ __launch_bounds__(256) void k_agg(const float* __restrict__ x,
                                             const float* __restrict__ att,
                                             const int* __restrict__ src,
                                             const int* __restrict__ offs,
                                             const float* __restrict__ WLT,
                                             const float* __restrict__ bias,
                                             float* __restrict__ Un,
                                             float* __restrict__ out) {
    constexpr int L = DIN / 2;        // lanes per edge (float2 each)
    constexpr int S = 64 / L;         // edge slots per wave
    constexpr int G = 64 / DOUT;      // k-groups for matmul
    constexpr int KS = DIN / G;       // k-slice per lane
    __shared__ float xm[4][DIN];
    int tid = threadIdx.x, w = tid >> 6, l = tid & 63;
    int n = blockIdx.x * 4 + w;
    int b = offs[n], e = offs[n + 1];
    int j = l & (L - 1), slot = l / L;
    int c = l & (DOUT - 1), g = l / DOUT;

    float Wreg[KS];
    #pragma unroll
    for (int kk = 0; kk < KS; ++kk) Wreg[kk] = WLT[(size_t)c * DIN + g * KS + kk];

    float ax = 0.f, ay = 0.f;
    int i = b + slot;
    for (; i + S < e; i += 2 * S) {
        float a0 = att[i], a1 = att[i + S];
        float2 p0 = *(const float2*)(x + (size_t)src[i] * DIN + 2 * j);
        float2 p1 = *(const float2*)(x + (size_t)src[i + S] * DIN + 2 * j);
        ax += a0 * p0.x + a1 * p1.x;
        ay += a0 * p0.y + a1 * p1.y;
    }
    for (; i < e; i += S) {
        float a0 = att[i];
        float2 p0 = *(const float2*)(x + (size_t)src[i] * DIN + 2 * j);
        ax += a0 * p0.x; ay += a0 * p0.y;
    }
    #pragma unroll
    for (int st = L; st < 64; st <<= 1) { ax += __shfl_xor(ax, st); ay += __shfl_xor(ay, st); }
    if (l < L) {
        float2 q = *(const float2*)(x + (size_t)n * DIN + 2 * j);
        *(float2*)&xm[w][2 * j] = make_float2(ax + q.x, ay + q.y);
    }
    __builtin_amdgcn_s_waitcnt(0);
    __builtin_amdgcn_sched_barrier(0);

    float o = 0.f;
    if constexpr (KS >= 4) {
        #pragma unroll
        for (int kk = 0; kk < KS; kk += 4) {
            float4 xv = *(const float4*)&xm[w][g * KS + kk];
            o += xv.x * Wreg[kk] + xv.y * Wreg[kk + 1] + xv.z * Wreg[kk + 2] + xv.w * Wreg[kk + 3];
        }
    } else {
        float2 xv = *(const float2*)&xm[w][g * KS];
        o += xv.x * Wreg[0] + xv.y * Wreg[1];
    }
    #pragma unroll
    for (int st = DOUT; st < 64; st <<= 1) o += __shfl_xor(o, st);

    float u = 0.f;
    if (l < DOUT) {
        u = lrelu(o + bias[l]);
        if (WU) Un[(size_t)n * DOUT + l] = u;
    }
    float ss = u * u;
    #pragma unroll
    for (int m = DOUT / 2; m >= 1; m >>= 1) ss += __shfl_xor(ss, m);
    if (l < DOUT) {
        float nrm = u * fast_rcp(fmaxf(sqrtf(ss), 1e-12f));
        #pragma unroll
        for (int rr = RSTART; rr < 4; ++rr)
            out[(size_t)rr * RES + (size_t)n * OUTW + COL + l] = nrm;
    }
}

// ---------------- all B-chains in ONE dispatch (LDS-resident intermediates) ----------------
// seg0: U1 -> W1 -> W2 -> W3 into result0 cols 96/112/128
// seg1: U2 -> W2 -> W3 into result1 cols 112/128
// seg2: U3 -> W3 into result2 col 128
__global__ __launch_bounds__(256) void k_bchain(const float* __restrict__ U1,
                                                const float* __restrict__ U2,
                                                const float* __restrict__ U3,
                                                const float* __restrict__ WLT,
                                                const float* __restrict__ b1,
                                                const float* __restrict__ b2,
                                                const float* __restrict__ b3,
                                                float* __restrict__ out) {
    __shared__ float W1s[16][33], W2s[16][17], W3s[8][17];
    __shared__ float bb1[16], bb2[16], bb3[8];
    __shared__ float row[16][33], mid[16][17], mid2[16][17];
    int tid = threadIdx.x;
    for (int id = tid; id < 512; id += 256) W1s[id >> 5][id & 31] = WLT[2048 + id];
    { int id = tid; if (id < 256) W2s[id >> 4][id & 15] = WLT[2560 + id]; }
    if (tid < 128) W3s[tid >> 4][tid & 15] = WLT[2816 + tid];
    if (tid < 16) bb1[tid] = b1[tid];
    if (tid >= 32 && tid < 48) bb2[tid - 32] = b2[tid - 32];
    if (tid >= 64 && tid < 72) bb3[tid - 64] = b3[tid - 64];
    __syncthreads();

    int grp = tid >> 4, lj = tid & 15;
    int seg = blockIdx.x / 6250;
    int nb = blockIdx.x % 6250;
    int n = nb * 16 + grp;

    if (seg == 0) {
        *(float2*)&row[grp][2 * lj] = *(const float2*)(U1 + (size_t)n * 32 + 2 * lj);
        __builtin_amdgcn_s_waitcnt(0);
        __builtin_amdgcn_sched_barrier(0);
        float o1 = bb1[lj];
        #pragma unroll
        for (int k = 0; k < 32; ++k) o1 += row[grp][k] * W1s[lj][k];
        float u1 = lrelu(o1);
        mid[grp][lj] = u1;
        float ss = u1 * u1;
        #pragma unroll
        for (int m = 8; m >= 1; m >>= 1) ss += __shfl_xor(ss, m);
        out[(size_t)n * OUTW + 96 + lj] = u1 * fast_rcp(fmaxf(sqrtf(ss), 1e-12f));
        __builtin_amdgcn_s_waitcnt(0);
        __builtin_amdgcn_sched_barrier(0);
        float o2 = bb2[lj];
        #pragma unroll
        for (int k = 0; k < 16; ++k) o2 += mid[grp][k] * W2s[lj][k];
        float u2 = lrelu(o2);
        mid2[grp][lj] = u2;
        float s2 = u2 * u2;
        #pragma unroll
        for (int m = 8; m >= 1; m >>= 1) s2 += __shfl_xor(s2, m);
        out[(size_t)n * OUTW + 112 + lj] = u2 * fast_rcp(fmaxf(sqrtf(s2), 1e-12f));
        __builtin_amdgcn_s_waitcnt(0);
        __builtin_amdgcn_sched_barrier(0);
        if (lj < 8) {
            float o3 = bb3[lj];
            #pragma unroll
            for (int k = 0; k < 16; ++k) o3 += mid2[grp][k] * W3s[lj][k];
            float u3 = lrelu(o3);
            float s3 = u3 * u3;
            #pragma unroll
            for (int m = 4; m >= 1; m >>= 1) s3 += __shfl_xor(s3, m);
            out[(size_t)n * OUTW + 128 + lj] = u3 * fast_rcp(fmaxf(sqrtf(s3), 1e-12f));
        }
    } else if (seg == 1) {
        mid[grp][lj] = U2[(size_t)n * 16 + lj];
        __builtin_amdgcn_s_waitcnt(0);
        __builtin_amdgcn_sched_barrier(0);
        float o2 = bb2[lj];
        #pragma unroll
        for (int k = 0; k < 16; ++k) o2 += mid[grp][k] * W2s[lj][k];
        float u2 = lrelu(o2);
        mid2[grp][lj] = u2;
        float s2 = u2 * u2;
        #pragma unroll
        for (int m = 8; m >= 1; m >>= 1) s2 += __shfl_xor(s2, m);
        out[RES + (size_t)n * OUTW + 112 + lj] = u2 * fast_rcp(fmaxf(sqrtf(s2), 1e-12f));
        __builtin_amdgcn_s_waitcnt(0);
        __builtin_amdgcn_sched_barrier(0);
        if (lj < 8) {
            float o3 = bb3[lj];
            #pragma unroll
            for (int k = 0; k < 16; ++k) o3 += mid2[grp][k] * W3s[lj][k];
            float u3 = lrelu(o3);
            float s3 = u3 * u3;
            #pragma unroll
            for (int m = 4; m >= 1; m >>= 1) s3 += __shfl_xor(s3, m);
            out[RES + (size_t)n * OUTW + 128 + lj] = u3 * fast_rcp(fmaxf(sqrtf(s3), 1e-12f));
        }
    } else {
        mid[grp][lj] = U3[(size_t)n * 16 + lj];
        __builtin_amdgcn_s_waitcnt(0);
        __builtin_amdgcn_sched_barrier(0);
        if (lj < 8) {
            float o3 = bb3[lj];
            #pragma unroll
            for (int k = 0; k < 16; ++k) o3 += mid[grp][k] * W3s[lj][k];
            float u3 = lrelu(o3);
            float s3 = u3 * u3;
            #pragma unroll
            for (int m = 4; m >= 1; m >>= 1) s3 += __shfl_xor(s3, m);
            out[2 * RES + (size_t)n * OUTW + 128 + lj] = u3 * fast_rcp(fmaxf(sqrtf(s3), 1e-12f));
        }
    }
}

// ---------------- emb block copy to all 4 results ----------------
__global__ __launch_bounds__(256) void k_emb_copy(const float* __restrict__ emb, float* __restrict__ out) {
    int idx = blockIdx.x * 256 + threadIdx.x;
    int n = idx >> 4, cc = (idx & 15) * 4;
    float4 v = *(const float4*)(emb + (size_t)n * 64 + cc);
    #pragma unroll
    for (int r = 0; r < 4; ++r)
        *(float4*)(out + (size_t)r * RES + (size_t)n * OUTW + cc) = v;
}

extern "C" void kernel_launch(void* const* d_in, const int* in_sizes, int n_in,
                              void* d_out, int out_size, void* d_ws, size_t ws_size,
                              hipStream_t stream) {
    (void)in_sizes; (void)n_in; (void)out_size;
    const float* emb = (const float*)d_in[0];
    const float* rel_embed = (const float*)d_in[1];
    const float* W_R = (const float*)d_in[2];
    const float* W0 = (const float*)d_in[3];  const float* b0 = (const float*)d_in[4];
    const float* W1 = (const float*)d_in[5];  const float* b1 = (const float*)d_in[6];
    const float* W2 = (const float*)d_in[7];  const float* b2 = (const float*)d_in[8];
    const float* W3 = (const float*)d_in[9];  const float* b3 = (const float*)d_in[10];
    const int* src = (const int*)d_in[11];
    const int* dst = (const int*)d_in[12];
    const int* etype = (const int*)d_in[13];
    float* out = (float*)d_out;

    char* p = (char*)d_ws;
    auto alloc = [&](size_t bytes) { char* q = p; p += (bytes + 255) & ~(size_t)255; return q; };
    int* offs  = (int*)alloc((size_t)(N_NODES + 1) * 4);
    float* att = (float*)alloc((size_t)N_EDGES * 4);
    int* eperm = (int*)alloc((size_t)N_EDGES * 4);
    int* srcp  = (int*)alloc((size_t)N_EDGES * 4);
    int* dstp  = (int*)alloc((size_t)N_EDGES * 4);
    int* cnt   = (int*)alloc(64);
    int* roff  = (int*)alloc(68);
    int* cur   = (int*)alloc(64);
    unsigned short* embB = (unsigned short*)alloc((size_t)N_NODES * 64 * 2);
    unsigned short* WT   = (unsigned short*)alloc((size_t)65536 * 2);
    float* WLT  = (float*)alloc((size_t)2944 * 4);
    float* U1   = (float*)alloc((size_t)N_NODES * 32 * 4);
    float* U2   = (float*)alloc((size_t)N_NODES * 16 * 4);
    float* U3   = (float*)alloc((size_t)N_NODES * 16 * 4);
    size_t fixed = (size_t)(p - (char*)d_ws);
    size_t per_rel = (size_t)N_NODES * 64 * 2;   // bf16 buf per relation
    int chunk = 1;
    if (ws_size > fixed + per_rel)
        chunk = (int)((ws_size - fixed) / per_rel);
    if (chunk > 4) chunk = 4;                    // keep footprint L2/L3-resident
    if (chunk < 1) chunk = 1;
    unsigned short* allbuf = (unsigned short*)p;

    // prep
    k_offsets<<<(N_NODES + 256) / 256, 256, 0, stream>>>(dst, offs);
    k_zero<<<1, 64, 0, stream>>>(cnt);
    k_hist<<<N_EDGES / 256, 256, 0, stream>>>(etype, cnt);
    k_scan<<<1, 64, 0, stream>>>(cnt, roff, cur);
    k_scatter<<<N_EDGES / 256, 256, 0, stream>>>(etype, src, dst, cur, eperm, srcp, dstp);
    k_cast_emb<<<N_NODES * 16 / 256, 256, 0, stream>>>(emb, embB);
    k_prep_wr<<<256, 256, 0, stream>>>(W_R, WT);
    k_prep_wl<<<12, 256, 0, stream>>>(W0, W1, W2, W3, WLT);

    // attention: chunked MFMA transform + edge scores (bufs stay cache-resident)
    for (int c0 = 0; c0 < N_RELS; c0 += chunk) {
        int nc = N_RELS - c0 < chunk ? N_RELS - c0 : chunk;
        k_gemm_mfma<<<(N_NODES + 127) / 128, 256, 0, stream>>>(embB, WT + (size_t)c0 * 4096, allbuf, nc);
        k_edge_att4<<<2048, 256, 0, stream>>>(allbuf, rel_embed, srcp, dstp, eperm, roff, c0, nc, att);
    }
    k_softmax<<<N_NODES / 32, 256, 0, stream>>>(att, offs);

    // A-chain
    k_agg1<<<N_NODES / 4, 256, 0, stream>>>(emb, embB, att, src, offs, WLT, b0, U1, out);
    k_agg<32, 16, 96, 1, true ><<<N_NODES / 4, 256, 0, stream>>>(U1, att, src, offs, WLT + 2048, b1, U2, out);
    k_agg<16, 16, 112, 2, true><<<N_NODES / 4, 256, 0, stream>>>(U2, att, src, offs, WLT + 2560, b2, U3, out);
    k_agg<16, 8, 128, 3, false><<<N_NODES / 4, 256, 0, stream>>>(U3, att, src, offs, WLT + 2816, b3, nullptr, out);

    // all B-chains, one dispatch
    k_bchain<<<18750, 256, 0, stream>>>(U1, U2, U3, WLT, b1, b2, b3, out);

    // emb block
    k_emb_copy<<<N_NODES * 16 / 256, 256, 0, stream>>>(emb, out);
}